// Round 11
// baseline (421.393 us; speedup 1.0000x reference)
//
#include <hip/hip_runtime.h>

#define LN_EPS 1e-5f

static constexpr int Hc  = 512;
static constexpr int Fc  = 16;
static constexpr int Sc  = 1024;
static constexpr int RPW = 16;       // rows per wave: same s, consecutive b

// ---- DPP wave64 sum: 6 VALU steps + readlane, no LDS, no barriers ----
template <int CTRL, int RMASK>
__device__ __forceinline__ float dpp_add(float v) {
    int t = __builtin_amdgcn_update_dpp(0, __float_as_int(v), CTRL, RMASK, 0xf, true);
    return v + __int_as_float(t);
}
__device__ __forceinline__ float wave_sum64(float v) {
    v = dpp_add<0x111, 0xf>(v);   // row_shr:1
    v = dpp_add<0x112, 0xf>(v);   // row_shr:2
    v = dpp_add<0x114, 0xf>(v);   // row_shr:4
    v = dpp_add<0x118, 0xf>(v);   // row_shr:8
    v = dpp_add<0x142, 0xa>(v);   // row_bcast:15
    v = dpp_add<0x143, 0xc>(v);   // row_bcast:31 -> lane63 has total
    return __int_as_float(__builtin_amdgcn_readlane(__float_as_int(v), 63));
}
__device__ __forceinline__ float rdlane(float v, int l) {
    return __int_as_float(__builtin_amdgcn_readlane(__float_as_int(v), l));
}

// bf16 RNE round (result in low 16 bits)
__device__ __forceinline__ unsigned rne16(float f) {
    unsigned u = __float_as_uint(f);
    return (u + 0x7fffu + ((u >> 16) & 1u)) >> 16;
}
__device__ __forceinline__ unsigned pack2(float lo, float hi) {
    return rne16(lo) | (rne16(hi) << 16);
}
// lo col: exact bf16 as f32 (1 shift). hi col: raw reg as f32 -> bf16(hi) with
// <=2^-8 rel mantissa noise from the lo bits -- free (0 ops), error ~ bf16 quant.
__device__ __forceinline__ float lo_f(unsigned p) { return __uint_as_float(p << 16); }
__device__ __forceinline__ float hi_f(unsigned p) { return __uint_as_float(p); }

// ---- single fused kernel: one wave per (g,s); rows b = g*16..g*16+15 ----
// W panel bf16-packed: 64 VGPR (was 128 f32) -> total ~112 -> 4 waves/SIMD
// (16 waves/CU, 2x R9) with NO inter-wave coupling (R10's barrier regressed).
// Zero VMEM loads in the t-loop; emb[s]+sum(b) folded into a per-wave register.
__global__ __launch_bounds__(256, 4) void fused_kernel(
    const float* __restrict__ x, const float* __restrict__ W,
    const float* __restrict__ b, const float* __restrict__ emb,
    const float* __restrict__ gamma, const float* __restrict__ beta,
    float* __restrict__ out)
{
    const int lane = threadIdx.x & 63;
    const int wid  = (blockIdx.x << 2) | (threadIdx.x >> 6);   // 0..8191
    const int s    = wid & (Sc - 1);
    const int g    = wid >> 10;                                // 0..7
    const int h0 = lane * 4, h1 = h0 + 256;

    // packed W panel: 16 K-rows x 8 cols per lane in 64 u32
    unsigned p00[Fc], p01[Fc], p10[Fc], p11[Fc];
#pragma unroll
    for (int i = 0; i < Fc; ++i) {
        const float4 wa = *reinterpret_cast<const float4*>(&W[i * Hc + h0]);
        const float4 wb = *reinterpret_cast<const float4*>(&W[i * Hc + h1]);
        p00[i] = pack2(wa.x, wa.y);
        p01[i] = pack2(wa.z, wa.w);
        p10[i] = pack2(wb.x, wb.y);
        p11[i] = pack2(wb.z, wb.w);
    }

    // x for all 16 rows up front: 4 gather loads (4 x 64B segments each)
    const int sub = lane >> 4, i16 = lane & 15;
    float xq0, xq1, xq2, xq3;
    {
        const size_t xoff = (size_t)s * Fc + i16;
        xq0 = __builtin_nontemporal_load(&x[(size_t)(g * 16 +  0 + sub) * Sc * Fc + xoff]);
        xq1 = __builtin_nontemporal_load(&x[(size_t)(g * 16 +  4 + sub) * Sc * Fc + xoff]);
        xq2 = __builtin_nontemporal_load(&x[(size_t)(g * 16 +  8 + sub) * Sc * Fc + xoff]);
        xq3 = __builtin_nontemporal_load(&x[(size_t)(g * 16 + 12 + sub) * Sc * Fc + xoff]);
    }

    // ebs = emb[s] + sum_i b[i]  (bsum folded in; no separate dispatch)
    float4 ebs0 = *reinterpret_cast<const float4*>(&emb[(size_t)s * Hc + h0]);
    float4 ebs1 = *reinterpret_cast<const float4*>(&emb[(size_t)s * Hc + h1]);
#pragma unroll
    for (int i = 0; i < Fc; ++i) {
        const float4 ba = *reinterpret_cast<const float4*>(&b[i * Hc + h0]);
        const float4 bb = *reinterpret_cast<const float4*>(&b[i * Hc + h1]);
        ebs0.x += ba.x; ebs0.y += ba.y; ebs0.z += ba.z; ebs0.w += ba.w;
        ebs1.x += bb.x; ebs1.y += bb.y; ebs1.z += bb.z; ebs1.w += bb.w;
    }

    const float4 g0  = *reinterpret_cast<const float4*>(&gamma[h0]);
    const float4 g1  = *reinterpret_cast<const float4*>(&gamma[h1]);
    const float4 be0 = *reinterpret_cast<const float4*>(&beta[h0]);
    const float4 be1 = *reinterpret_cast<const float4*>(&beta[h1]);

#pragma unroll
    for (int t = 0; t < RPW; ++t) {
        const float xsrc = (t >> 2) == 0 ? xq0 : (t >> 2) == 1 ? xq1 : (t >> 2) == 2 ? xq2 : xq3;
        float xs[Fc];
#pragma unroll
        for (int i = 0; i < Fc; ++i)
            xs[i] = rdlane(xsrc, (t & 3) * 16 + i);

        // pure-register FMA chain; per K: 4 shifts + 8 fma
        float4 a0 = ebs0, a1 = ebs1;
#pragma unroll
        for (int i = 0; i < Fc; ++i) {
            const float xi = xs[i];
            a0.x = fmaf(xi, lo_f(p00[i]), a0.x);
            a0.y = fmaf(xi, hi_f(p00[i]), a0.y);
            a0.z = fmaf(xi, lo_f(p01[i]), a0.z);
            a0.w = fmaf(xi, hi_f(p01[i]), a0.w);
            a1.x = fmaf(xi, lo_f(p10[i]), a1.x);
            a1.y = fmaf(xi, hi_f(p10[i]), a1.y);
            a1.z = fmaf(xi, lo_f(p11[i]), a1.z);
            a1.w = fmaf(xi, hi_f(p11[i]), a1.w);
        }

        float psum = a0.x + a0.y + a0.z + a0.w + a1.x + a1.y + a1.z + a1.w;
        float pssq = fmaf(a0.x, a0.x, fmaf(a0.y, a0.y, fmaf(a0.z, a0.z, a0.w * a0.w)));
        pssq = fmaf(a1.x, a1.x, fmaf(a1.y, a1.y, fmaf(a1.z, a1.z, fmaf(a1.w, a1.w, pssq))));

        const float sum = wave_sum64(psum);
        const float ssq = wave_sum64(pssq);

        const float mean = sum * (1.0f / 512.0f);
        const float var  = ssq * (1.0f / 512.0f) - mean * mean;
        const float rs   = rsqrtf(var + LN_EPS);
        const float nmrs = -mean * rs;   // (a-mean)*rs == fma(a, rs, nmrs)

        float4 r0, r1;
        r0.x = fmaf(fmaf(a0.x, rs, nmrs), g0.x, be0.x);
        r0.y = fmaf(fmaf(a0.y, rs, nmrs), g0.y, be0.y);
        r0.z = fmaf(fmaf(a0.z, rs, nmrs), g0.z, be0.z);
        r0.w = fmaf(fmaf(a0.w, rs, nmrs), g0.w, be0.w);
        r1.x = fmaf(fmaf(a1.x, rs, nmrs), g1.x, be1.x);
        r1.y = fmaf(fmaf(a1.y, rs, nmrs), g1.y, be1.y);
        r1.z = fmaf(fmaf(a1.z, rs, nmrs), g1.z, be1.z);
        r1.w = fmaf(fmaf(a1.w, rs, nmrs), g1.w, be1.w);

        float* orow = out + ((size_t)(g * 16 + t) * Sc + s) * Hc;
        *reinterpret_cast<float4*>(&orow[h0]) = r0;
        *reinterpret_cast<float4*>(&orow[h1]) = r1;
    }
}

extern "C" void kernel_launch(void* const* d_in, const int* in_sizes, int n_in,
                              void* d_out, int out_size, void* d_ws, size_t ws_size,
                              hipStream_t stream) {
    const float* x     = (const float*)d_in[0];
    const float* W     = (const float*)d_in[1];
    const float* b     = (const float*)d_in[2];
    const float* emb   = (const float*)d_in[3];
    const float* gamma = (const float*)d_in[4];
    const float* beta  = (const float*)d_in[5];
    float* out = (float*)d_out;

    const int blocks = (8 * Sc) / 4;   // 8192 waves, 4 per block
    fused_kernel<<<blocks, 256, 0, stream>>>(x, W, b, emb, gamma, beta, out);
}

// Round 12
// 66.055 us; speedup vs baseline: 6.3795x; 6.3795x over previous
//
#include <hip/hip_runtime.h>

#define LN_EPS 1e-5f

static constexpr int Hc  = 512;
static constexpr int Fc  = 16;
static constexpr int Sc  = 1024;
static constexpr int RPW = 16;       // rows per wave: same s, consecutive b

// ---- prologue: bsum[h] = sum_i b[i][h] (512 floats into d_ws) ----
__global__ void bsum_kernel(const float* __restrict__ b, float* __restrict__ bsum) {
    int h = blockIdx.x * 64 + threadIdx.x;
    float s = 0.f;
#pragma unroll
    for (int i = 0; i < Fc; ++i) s += b[i * Hc + h];
    bsum[h] = s;
}

// ---- DPP wave64 sum: 6 VALU steps + readlane, no LDS, no barriers ----
template <int CTRL, int RMASK>
__device__ __forceinline__ float dpp_add(float v) {
    int t = __builtin_amdgcn_update_dpp(0, __float_as_int(v), CTRL, RMASK, 0xf, true);
    return v + __int_as_float(t);
}
__device__ __forceinline__ float wave_sum64(float v) {
    v = dpp_add<0x111, 0xf>(v);   // row_shr:1
    v = dpp_add<0x112, 0xf>(v);   // row_shr:2
    v = dpp_add<0x114, 0xf>(v);   // row_shr:4
    v = dpp_add<0x118, 0xf>(v);   // row_shr:8
    v = dpp_add<0x142, 0xa>(v);   // row_bcast:15
    v = dpp_add<0x143, 0xc>(v);   // row_bcast:31 -> lane63 has total
    return __int_as_float(__builtin_amdgcn_readlane(__float_as_int(v), 63));
}
__device__ __forceinline__ float rdlane(float v, int l) {
    return __int_as_float(__builtin_amdgcn_readlane(__float_as_int(v), l));
}

// bf16 RNE round; pack two cols per u32.
__device__ __forceinline__ unsigned rne16(float f) {
    unsigned u = __float_as_uint(f);
    return (u + 0x7fffu + ((u >> 16) & 1u)) >> 16;
}
__device__ __forceinline__ unsigned pack2(float lo, float hi) {
    return rne16(lo) | (rne16(hi) << 16);
}
// lo col: exact bf16 as f32 (1 shift). hi col: raw reg as f32 == bf16(hi) plus
// <=2^-8 rel mantissa noise from the lo bits -- free (0 ops), err ~ bf16 quant.
__device__ __forceinline__ float lo_f(unsigned p) { return __uint_as_float(p << 16); }
__device__ __forceinline__ float hi_f(unsigned p) { return __uint_as_float(p); }

// ---- fused: one wave per (g,s); rows b = g*16..g*16+15 ----
// R12 = R9 structure (zero VMEM loads in the t-loop, no inter-wave coupling)
// with the W panel bf16-PACKED: 64 VGPR instead of 128 f32. Target: natural
// VGPR <= 128 -> 4 waves/SIMD + register slack so consecutive rows' store
// data live in distinct regs (stores hold VGPRs until vmcnt consumes them --
// reg reuse forces per-row vmcnt waits; memset avoids this by storing a
// constant, which is why it sustains 7 TB/s at the same occupancy).
// NO min-waves arg: hipcc caps VGPR at ~256/w and spills (R4: 84, R11: 64).
__global__ __launch_bounds__(256) void fused_kernel(
    const float* __restrict__ x, const float* __restrict__ W,
    const float* __restrict__ emb, const float* __restrict__ bsum,
    const float* __restrict__ gamma, const float* __restrict__ beta,
    float* __restrict__ out)
{
    const int lane = threadIdx.x & 63;
    const int wid  = (blockIdx.x << 2) | (threadIdx.x >> 6);   // 0..8191
    const int s    = wid & (Sc - 1);
    const int g    = wid >> 10;                                // 0..7
    const int h0 = lane * 4, h1 = h0 + 256;

    // packed W panel: 16 K-rows x 8 cols per lane in 64 u32
    unsigned p00[Fc], p01[Fc], p10[Fc], p11[Fc];
#pragma unroll
    for (int i = 0; i < Fc; ++i) {
        const float4 wa = *reinterpret_cast<const float4*>(&W[i * Hc + h0]);
        const float4 wb = *reinterpret_cast<const float4*>(&W[i * Hc + h1]);
        p00[i] = pack2(wa.x, wa.y);
        p01[i] = pack2(wa.z, wa.w);
        p10[i] = pack2(wb.x, wb.y);
        p11[i] = pack2(wb.z, wb.w);
    }

    // x for all 16 rows up front: 4 gather loads (4 x 64B segments each)
    const int sub = lane >> 4, i16 = lane & 15;
    float xq0, xq1, xq2, xq3;
    {
        const size_t xoff = (size_t)s * Fc + i16;
        xq0 = __builtin_nontemporal_load(&x[(size_t)(g * 16 +  0 + sub) * Sc * Fc + xoff]);
        xq1 = __builtin_nontemporal_load(&x[(size_t)(g * 16 +  4 + sub) * Sc * Fc + xoff]);
        xq2 = __builtin_nontemporal_load(&x[(size_t)(g * 16 +  8 + sub) * Sc * Fc + xoff]);
        xq3 = __builtin_nontemporal_load(&x[(size_t)(g * 16 + 12 + sub) * Sc * Fc + xoff]);
    }

    // loop-invariant per-wave vectors
    const float4 g0  = *reinterpret_cast<const float4*>(&gamma[h0]);
    const float4 g1  = *reinterpret_cast<const float4*>(&gamma[h1]);
    const float4 be0 = *reinterpret_cast<const float4*>(&beta[h0]);
    const float4 be1 = *reinterpret_cast<const float4*>(&beta[h1]);
    float4 ebs0, ebs1;
    {
        const float4 e0  = *reinterpret_cast<const float4*>(&emb[(size_t)s * Hc + h0]);
        const float4 e1  = *reinterpret_cast<const float4*>(&emb[(size_t)s * Hc + h1]);
        const float4 bs0 = *reinterpret_cast<const float4*>(&bsum[h0]);
        const float4 bs1 = *reinterpret_cast<const float4*>(&bsum[h1]);
        ebs0.x = e0.x + bs0.x; ebs0.y = e0.y + bs0.y; ebs0.z = e0.z + bs0.z; ebs0.w = e0.w + bs0.w;
        ebs1.x = e1.x + bs1.x; ebs1.y = e1.y + bs1.y; ebs1.z = e1.z + bs1.z; ebs1.w = e1.w + bs1.w;
    }

#pragma unroll
    for (int t = 0; t < RPW; ++t) {
        const float xsrc = (t >> 2) == 0 ? xq0 : (t >> 2) == 1 ? xq1 : (t >> 2) == 2 ? xq2 : xq3;

        // pure-register FMA chain; W unpacked on the fly (4 shifts + 8 fma / K)
        float4 a0 = ebs0, a1 = ebs1;
#pragma unroll
        for (int i = 0; i < Fc; ++i) {
            const float xi = rdlane(xsrc, (t & 3) * 16 + i);   // SGPR broadcast
            a0.x = fmaf(xi, lo_f(p00[i]), a0.x);
            a0.y = fmaf(xi, hi_f(p00[i]), a0.y);
            a0.z = fmaf(xi, lo_f(p01[i]), a0.z);
            a0.w = fmaf(xi, hi_f(p01[i]), a0.w);
            a1.x = fmaf(xi, lo_f(p10[i]), a1.x);
            a1.y = fmaf(xi, hi_f(p10[i]), a1.y);
            a1.z = fmaf(xi, lo_f(p11[i]), a1.z);
            a1.w = fmaf(xi, hi_f(p11[i]), a1.w);
        }

        float psum = a0.x + a0.y + a0.z + a0.w + a1.x + a1.y + a1.z + a1.w;
        float pssq = fmaf(a0.x, a0.x, fmaf(a0.y, a0.y, fmaf(a0.z, a0.z, a0.w * a0.w)));
        pssq = fmaf(a1.x, a1.x, fmaf(a1.y, a1.y, fmaf(a1.z, a1.z, fmaf(a1.w, a1.w, pssq))));

        const float sum = wave_sum64(psum);
        const float ssq = wave_sum64(pssq);

        const float mean = sum * (1.0f / 512.0f);
        const float var  = ssq * (1.0f / 512.0f) - mean * mean;
        const float rs   = rsqrtf(var + LN_EPS);
        const float nmrs = -mean * rs;   // (a-mean)*rs == fma(a, rs, nmrs)

        float4 r0, r1;
        r0.x = fmaf(fmaf(a0.x, rs, nmrs), g0.x, be0.x);
        r0.y = fmaf(fmaf(a0.y, rs, nmrs), g0.y, be0.y);
        r0.z = fmaf(fmaf(a0.z, rs, nmrs), g0.z, be0.z);
        r0.w = fmaf(fmaf(a0.w, rs, nmrs), g0.w, be0.w);
        r1.x = fmaf(fmaf(a1.x, rs, nmrs), g1.x, be1.x);
        r1.y = fmaf(fmaf(a1.y, rs, nmrs), g1.y, be1.y);
        r1.z = fmaf(fmaf(a1.z, rs, nmrs), g1.z, be1.z);
        r1.w = fmaf(fmaf(a1.w, rs, nmrs), g1.w, be1.w);

        float* orow = out + ((size_t)(g * 16 + t) * Sc + s) * Hc;
        *reinterpret_cast<float4*>(&orow[h0]) = r0;
        *reinterpret_cast<float4*>(&orow[h1]) = r1;
    }
}

extern "C" void kernel_launch(void* const* d_in, const int* in_sizes, int n_in,
                              void* d_out, int out_size, void* d_ws, size_t ws_size,
                              hipStream_t stream) {
    const float* x     = (const float*)d_in[0];
    const float* W     = (const float*)d_in[1];
    const float* b     = (const float*)d_in[2];
    const float* emb   = (const float*)d_in[3];
    const float* gamma = (const float*)d_in[4];
    const float* beta  = (const float*)d_in[5];
    float* out  = (float*)d_out;
    float* bsum = (float*)d_ws;     // 512 floats

    bsum_kernel<<<Hc / 64, 64, 0, stream>>>(b, bsum);

    const int blocks = (8 * Sc) / 4;   // 8192 waves, 4 per block
    fused_kernel<<<blocks, 256, 0, stream>>>(x, W, emb, bsum, gamma, beta, out);
}